// Round 1
// 1105.581 us; speedup vs baseline: 1.1770x; 1.1770x over previous
//
#include <hip/hip_runtime.h>
#include <math.h>

#define B_ROWS 8192
#define V_COLS 32000
#define K_NEG  5
#define S_DOM  100
#define EPSF   1e-10f

// Key algebraic fact: the reference's stability shift m (the detached row max)
// cancels exactly in out = v / sum(v) -- every v_j carries e^{-m}. The loss is
// therefore independent of the row max, and we never need to read the full
// 32000-wide row (1.05 GB total). We gather only the 6 logits that matter and
// use a LOCAL shift (max of those 6) for overflow safety, which is free.
//
// One thread per row: ~12 mostly-independent loads (y, 5x ind, 5x prob gather
// [12.8 MB table, L2/L3-resident], 6x scattered yHat loads) + ~12 exp/log.
__global__ __launch_bounds__(256) void blackout_gather_kernel(
    const float* __restrict__ yHat,
    const float* __restrict__ prob,
    const int*   __restrict__ y,
    const int*   __restrict__ ind,
    float*       __restrict__ row_loss)
{
    const int r = blockIdx.x * 256 + threadIdx.x;
    if (r >= B_ROWS) return;

    const int yy = y[r];
    const float* __restrict__ row  = yHat + (size_t)r  * V_COLS;
    const float* __restrict__ prow = prob + (size_t)yy * S_DOM;

    // Issue all index loads first (independent, coalesced-ish: 5 ints/thread).
    int ij[K_NEG];
    #pragma unroll
    for (int j = 0; j < K_NEG; ++j)
        ij[j] = ind[r * K_NEG + j];          // in [0, 100)

    // Gather logits + importance weights.
    const float t = row[yy];
    float p[K_NEG], c[K_NEG];
    float q = INFINITY;
    float m = t;                             // local stability shift
    #pragma unroll
    for (int j = 0; j < K_NEG; ++j) {
        p[j] = 1.0f / prow[ij[j]];
        q    = fminf(q, p[j]);
        c[j] = row[ij[j]];
        m    = fmaxf(m, c[j]);
    }

    // v_0 = q*exp(t-m), v_j = p_j*exp(c_j-m); shift m cancels in v/sum.
    const float v0 = q * expf(t - m);
    float sum = v0;
    float v[K_NEG];
    #pragma unroll
    for (int j = 0; j < K_NEG; ++j) {
        v[j] = p[j] * expf(c[j] - m);
        sum += v[j];
    }
    const float inv_sum = 1.0f / sum;

    // loss_r = log(out0+eps) + sum_{j>=1} log(1 - out_j + eps)
    float lr = logf(v0 * inv_sum + EPSF);
    #pragma unroll
    for (int j = 0; j < K_NEG; ++j)
        lr += logf(1.0f - v[j] * inv_sum + EPSF);

    row_loss[r] = lr;
}

__global__ __launch_bounds__(256) void blackout_reduce_kernel(
    const float* __restrict__ row_loss,
    float*       __restrict__ out)
{
    const int tid = threadIdx.x;
    float s = 0.0f;
    for (int i = tid; i < B_ROWS; i += 256)
        s += row_loss[i];
    #pragma unroll
    for (int off = 32; off > 0; off >>= 1)
        s += __shfl_down(s, off, 64);
    __shared__ float sh[4];
    if ((tid & 63) == 0) sh[tid >> 6] = s;
    __syncthreads();
    if (tid == 0) {
        const float tot = sh[0] + sh[1] + sh[2] + sh[3];
        out[0] = -tot / (float)(B_ROWS * (K_NEG + 1));
    }
}

extern "C" void kernel_launch(void* const* d_in, const int* in_sizes, int n_in,
                              void* d_out, int out_size, void* d_ws, size_t ws_size,
                              hipStream_t stream) {
    const float* yHat = (const float*)d_in[0];   // [8192, 32000] f32
    const float* prob = (const float*)d_in[1];   // [32000, 100] f32
    const int*   y    = (const int*)d_in[2];     // [8192]
    const int*   ind  = (const int*)d_in[3];     // [8192, 5]
    float* out = (float*)d_out;                  // scalar
    float* row_loss = (float*)d_ws;              // 8192 floats scratch

    blackout_gather_kernel<<<B_ROWS / 256, 256, 0, stream>>>(yHat, prob, y, ind, row_loss);
    blackout_reduce_kernel<<<1, 256, 0, stream>>>(row_loss, out);
}